// Round 12
// baseline (100.030 us; speedup 1.0000x reference)
//
#include <hip/hip_runtime.h>
#include <hip/hip_bf16.h>

namespace {

constexpr int T = 5, F = 30, H = 20;
constexpr int BATCH = 131072;
constexpr int BPB = 64;    // batch rows per block (16 per wave)
constexpr int XRS = 20;    // xsb row stride in dwords (40 halfwords / 80 B)
constexpr int HRS = 120;   // hist row stride in halfwords (240 B / 60 dwords)

typedef __attribute__((ext_vector_type(8))) short bf16x8;
typedef __attribute__((ext_vector_type(4))) float f32x4;

union Frag16 { uint2 d2[2]; uint4 d4; unsigned u32[4]; bf16x8 v; };
union Pack2 { __hip_bfloat162 h2; unsigned u; };

__device__ __forceinline__ float sig(float v) {
  return __builtin_amdgcn_rcpf(1.0f + __builtin_amdgcn_exp2f(v * -1.44269504f));
}
// tanh(v) = 2*sigmoid(2v) - 1; saturates correctly at +-inf, no NaN paths.
__device__ __forceinline__ float tanh_s(float v) {
  return fmaf(2.0f,
              __builtin_amdgcn_rcpf(1.0f + __builtin_amdgcn_exp2f(v * -2.88539008f)),
              -1.0f);
}
// round-to-nearest-even f32 -> bf16 bits (inputs tanh-bounded, no NaN/inf)
__device__ __forceinline__ unsigned short f2bf(float f) {
  unsigned u = __float_as_uint(f);
  return (unsigned short)((u + 0x7FFFu + ((u >> 16) & 1u)) >> 16);
}

// ---- setup: pre-pack the 640 MFMA A-fragments into d_ws ----
// item i: lane = i&63, sel = (i>>6)&1 (0=W,1=U), m = i>>7 (0..4).
// W rows hidx = 4*jj + gate; bias folded at k==30 (x virtual col 30 == 1.0).
// Invariant: U rows k>=20 are ZERO and W row k=31 is ZERO -- main kernel
// relies on this so B-fragment slots at k>=20 contribute 0 (they are ZEROED
// in LDS, never garbage: 0*Inf=NaN was the R11 failure).
__global__ void lstm_pack(
    const float* __restrict__ wf, const float* __restrict__ wi,
    const float* __restrict__ wo, const float* __restrict__ wc,
    const float* __restrict__ uf, const float* __restrict__ ui,
    const float* __restrict__ uo, const float* __restrict__ uc,
    const float* __restrict__ bf, const float* __restrict__ bi,
    const float* __restrict__ bo, const float* __restrict__ bc,
    bf16x8* __restrict__ ws)
{
  const int i = blockIdx.x * 256 + threadIdx.x;
  if (i >= 640) return;
  const int lane = i & 63, sel = (i >> 6) & 1, m = i >> 7;
  const int r15 = lane & 15, q = lane >> 4;
  const int gA = r15 & 3, jA = r15 >> 2;
  const int jj = 4 * m + jA;

  const float* Wg = (gA == 0) ? wf : (gA == 1) ? wi : (gA == 2) ? wo : wc;
  const float* Ug = (gA == 0) ? uf : (gA == 1) ? ui : (gA == 2) ? uo : uc;
  const float* Bg = (gA == 0) ? bf : (gA == 1) ? bi : (gA == 2) ? bo : bc;

  Frag16 fr;
#pragma unroll
  for (int e = 0; e < 4; ++e) {
    const int k0 = 8 * q + 2 * e, k1 = k0 + 1;
    float v0, v1;
    if (sel == 0) {
      v0 = (k0 < F) ? Wg[k0 * H + jj] : (k0 == F ? Bg[jj] : 0.f);
      v1 = (k1 < F) ? Wg[k1 * H + jj] : 0.f;
    } else {
      v0 = (k0 < H) ? Ug[k0 * H + jj] : 0.f;
      v1 = (k1 < H) ? Ug[k1 * H + jj] : 0.f;
    }
    Pack2 p; p.h2 = __float22bfloat162_rn(float2{v0, v1});
    fr.u32[e] = p.u;
  }
  ws[(m * 2 + sel) * 64 + lane] = fr.v;   // [m][sel][lane] -> coalesced reads
}

// ---- main: barrier-free, wave-private LDS rows.
// LDS = 20,480 B EXACTLY -> 8 blocks/CU -> all 2048/256=8 blocks per CU
// co-resident in ONE generation (kills the R10 straggler generation).
__global__ __launch_bounds__(256, 8) void lstm_main(
    const float* __restrict__ x,
    const bf16x8* __restrict__ wsfrag,
    float* __restrict__ out)
{
  const int tid  = threadIdx.x;
  const int lane = tid & 63;
  const int wv   = tid >> 6;
  const int r15  = lane & 15;
  const int q    = lane >> 4;
  const int b0   = blockIdx.x * BPB;
  const int w0   = 16 * wv;

  const float* xwave = x + (size_t)(b0 + w0) * (T * F);   // contiguous 9.6 KB
  float*       owave = out + (size_t)(b0 + w0) * (T * H); // contiguous 6.4 KB

  // xsb: bf16 x tile in fragment layout. Row r: hw k=0..29 = bf16(x), hw30 =
  // 1.0 (bias col), hw31 = 0, hw32..39 pad. 5,120 B.
  __shared__ __align__(16) unsigned xsb[BPB * XRS];
  // hist: bf16 h history, row layout [t][24] (jj 0..19 + 4 dead slots).
  // Serves BOTH the recurrent fh reads and the final drain. 15,360 B.
  // Row stride 60 dw -> 2-way bank aliasing (free); uint2 reads 8B-aligned.
  __shared__ __align__(16) unsigned short hist[BPB * HRS];

  // ---- ZERO this wave's hist rows (R11 NaN fix). fh reads dead slots
  // (hw 20..23 per t-block) and block t's hw 0..7 before they're written;
  // those must be 0.0, not uninit garbage (bf16 Inf/NaN * 0 = NaN in MFMA).
  {
    uint4* hz = (uint4*)(hist + w0 * HRS);   // wave-private 3,840 B, 16B-aligned
    const uint4 z = uint4{0u, 0u, 0u, 0u};
#pragma unroll
    for (int k = 0; k < 4; ++k) {
      int idx = lane + 64 * k;
      if (idx < 240) hz[idx] = z;
    }
  }

  // prologue: 10 coalesced dwordx4 fragment loads
  bf16x8 wfrag[5], ufrag[5];
#pragma unroll
  for (int m = 0; m < 5; ++m) {
    wfrag[m] = wsfrag[(m * 2 + 0) * 64 + lane];
    ufrag[m] = wsfrag[(m * 2 + 1) * 64 + lane];
  }

  // bias/zero constant dword (hw30=1.0, hw31=0) for all 64 rows, once.
  // (tid<64 = wave 0 writing rows 0..63: other waves only READ these after
  // their own first fx read; wave 0 writes them before any of ITS reads.
  // Cross-wave: xsb row r is only ever read by the wave owning r... rows are
  // wave-private (w0+r15), and wave 0 writes rows 0..63 -- cross-wave write!
  // Safe ONLY because waves that read early may race. Make it wave-local:)
#pragma unroll
  for (int k = 0; k < 1; ++k) {
    if (r15 < 16 && q == 0) { /* one lane group per row quartet */ }
  }
  // wave-local bias init: each wave writes its own 16 rows (lane 0..15 only)
  if (lane < 16) xsb[(w0 + lane) * XRS + 15] = 0x00003F80u;

  // stage x(t=0): slot s: r=s>>4, cs=s&15 (15 of 16 active), cols 2cs,2cs+1
#pragma unroll
  for (int j = 0; j < 4; ++j) {
    int s = lane + 64 * j;
    int r = s >> 4, cs = s & 15;
    if (cs < 15) {
      float2 v = *(const float2*)(xwave + r * (T * F) + 2 * cs);
      Pack2 p; p.h2 = __float22bfloat162_rn(v);
      xsb[(w0 + r) * XRS + cs] = p.u;
    }
  }

  float cst[5];
#pragma unroll
  for (int m = 0; m < 5; ++m) cst[m] = 0.f;
  float2 pf2[4];

#pragma unroll
  for (int t = 0; t < T; ++t) {
    // fx: single b128 from fragment-layout LDS (bias baked in, no cvt)
    Frag16 fx;
    fx.d4 = *(const uint4*)&xsb[(w0 + r15) * XRS + 4 * q];

    // T14: issue next-t global loads now; cvt+LDS-write land after compute
    if (t + 1 < T) {
#pragma unroll
      for (int j = 0; j < 4; ++j) {
        int s = lane + 64 * j;
        int r = s >> 4, cs = s & 15;
        if (cs < 15)
          pf2[j] = *(const float2*)(xwave + r * (T * F) + (t + 1) * F + 2 * cs);
      }
    }

    f32x4 acc[5];
#pragma unroll
    for (int m = 0; m < 5; ++m)
      acc[m] = __builtin_amdgcn_mfma_f32_16x16x32_bf16(
          wfrag[m], fx.v, f32x4{0.f, 0.f, 0.f, 0.f}, 0, 0, 0);

    if (t > 0) {   // recurrent term (t=0: h==0, matches reference)
      // fh from hist: hw 24(t-1)+8q.. ; slots at k>=20 are ZERO (prologue
      // memset / not-yet-written block t slots) and meet zero U-rows.
      Frag16 fh;
      const unsigned short* hp = &hist[(w0 + r15) * HRS + 24 * (t - 1) + 8 * q];
      fh.d2[0] = *(const uint2*)(hp);
      fh.d2[1] = *(const uint2*)(hp + 4);
#pragma unroll
      for (int m = 0; m < 5; ++m)
        acc[m] = __builtin_amdgcn_mfma_f32_16x16x32_bf16(
            ufrag[m], fh.v, acc[m], 0, 0, 0);
    }

    // gate math: lane-local (acc[m] = f,i,o,c of hidden jj=4m+q, own row)
#pragma unroll
    for (int m = 0; m < 5; ++m) {
      float fg = sig(acc[m][0]);
      float ig = sig(acc[m][1]);
      float og = sig(acc[m][2]);
      float ch = tanh_s(acc[m][3]);
      float cn = fmaf(fg, cst[m], ig * ch);
      cst[m] = cn;
      float hn = og * tanh_s(cn);
      hist[(w0 + r15) * HRS + 24 * t + 4 * m + q] = f2bf(hn);
    }

    // write staged x(t+1) (after this t's fx read -- program order)
    if (t + 1 < T) {
#pragma unroll
      for (int j = 0; j < 4; ++j) {
        int s = lane + 64 * j;
        int r = s >> 4, cs = s & 15;
        if (cs < 15) {
          Pack2 p; p.h2 = __float22bfloat162_rn(pf2[j]);
          xsb[(w0 + r) * XRS + cs] = p.u;
        }
      }
    }
  }

  // drain: wave's contiguous 6.4 KB out slab, full-line float4 stores.
  // g in [0,400): out dwords 4g..4g+3 = row r=g/25, cols c4..c4+3 (c4=4(g%25));
  // src hw = 24*(c4/20) + c4%20 (never crosses a t-block: 20 % 4 == 0).
#pragma unroll
  for (int k = 0; k < 7; ++k) {
    unsigned g = lane + 64 * k;
    if (g < 400) {
      unsigned r = g / 25u, c4 = 4 * (g % 25u);
      unsigned tb = c4 / 20u, j0 = c4 % 20u;
      uint2 pv = *(const uint2*)&hist[(w0 + r) * HRS + 24 * tb + j0];
      float4 v;
      v.x = __uint_as_float(pv.x << 16);
      v.y = __uint_as_float(pv.x & 0xFFFF0000u);
      v.z = __uint_as_float(pv.y << 16);
      v.w = __uint_as_float(pv.y & 0xFFFF0000u);
      *(float4*)(owave + 4 * g) = v;
    }
  }
}

} // namespace

extern "C" void kernel_launch(void* const* d_in, const int* in_sizes, int n_in,
                              void* d_out, int out_size, void* d_ws, size_t ws_size,
                              hipStream_t stream) {
  const float* x  = (const float*)d_in[0];
  const float* wf = (const float*)d_in[1];
  const float* wi = (const float*)d_in[2];
  const float* wo = (const float*)d_in[3];
  const float* wc = (const float*)d_in[4];
  const float* uf = (const float*)d_in[5];
  const float* ui = (const float*)d_in[6];
  const float* uo = (const float*)d_in[7];
  const float* uc = (const float*)d_in[8];
  const float* bf = (const float*)d_in[9];
  const float* bi = (const float*)d_in[10];
  const float* bo = (const float*)d_in[11];
  const float* bc = (const float*)d_in[12];
  float* out = (float*)d_out;
  bf16x8* ws = (bf16x8*)d_ws;   // needs 10,240 B

  hipLaunchKernelGGL(lstm_pack, dim3(3), dim3(256), 0, stream,
                     wf, wi, wo, wc, uf, ui, uo, uc, bf, bi, bo, bc, ws);
  hipLaunchKernelGGL(lstm_main, dim3(BATCH / BPB), dim3(256), 0, stream,
                     x, ws, out);
}

// Round 13
// 40.407 us; speedup vs baseline: 2.4755x; 2.4755x over previous
//
#include <hip/hip_runtime.h>
#include <hip/hip_bf16.h>

namespace {

constexpr int T = 5, F = 30, H = 20;
constexpr int BATCH = 131072;
constexpr int BPB = 64;    // batch rows per block (16 per wave)
constexpr int XRS = 20;    // xsb row stride in dwords (40 halfwords / 80 B)
constexpr int HRS = 120;   // hist row stride in halfwords (240 B / 60 dwords)

typedef __attribute__((ext_vector_type(8))) short bf16x8;
typedef __attribute__((ext_vector_type(4))) float f32x4;

union Frag16 { uint2 d2[2]; uint4 d4; unsigned u32[4]; bf16x8 v; };
union Pack2 { __hip_bfloat162 h2; unsigned u; };

__device__ __forceinline__ float sig(float v) {
  return __builtin_amdgcn_rcpf(1.0f + __builtin_amdgcn_exp2f(v * -1.44269504f));
}
// tanh(v) = 2*sigmoid(2v) - 1; saturates correctly at +-inf, no NaN paths.
__device__ __forceinline__ float tanh_s(float v) {
  return fmaf(2.0f,
              __builtin_amdgcn_rcpf(1.0f + __builtin_amdgcn_exp2f(v * -2.88539008f)),
              -1.0f);
}
// round-to-nearest-even f32 -> bf16 bits (inputs tanh-bounded, no NaN/inf)
__device__ __forceinline__ unsigned short f2bf(float f) {
  unsigned u = __float_as_uint(f);
  return (unsigned short)((u + 0x7FFFu + ((u >> 16) & 1u)) >> 16);
}

// ---- setup: pre-pack the 640 MFMA A-fragments into d_ws ----
// item i: lane = i&63, sel = (i>>6)&1 (0=W,1=U), m = i>>7 (0..4).
// W rows hidx = 4*jj + gate; bias folded at k==30 (x virtual col 30 == 1.0).
// Invariant: U rows k>=20 are ZERO and W row k=31 is ZERO -- main kernel
// relies on this so B-fragment slots at k>=20 contribute 0 (those LDS slots
// are zero-initialized, never garbage: 0*Inf=NaN was the R11 failure).
__global__ void lstm_pack(
    const float* __restrict__ wf, const float* __restrict__ wi,
    const float* __restrict__ wo, const float* __restrict__ wc,
    const float* __restrict__ uf, const float* __restrict__ ui,
    const float* __restrict__ uo, const float* __restrict__ uc,
    const float* __restrict__ bf, const float* __restrict__ bi,
    const float* __restrict__ bo, const float* __restrict__ bc,
    bf16x8* __restrict__ ws)
{
  const int i = blockIdx.x * 256 + threadIdx.x;
  if (i >= 640) return;
  const int lane = i & 63, sel = (i >> 6) & 1, m = i >> 7;
  const int r15 = lane & 15, q = lane >> 4;
  const int gA = r15 & 3, jA = r15 >> 2;
  const int jj = 4 * m + jA;

  const float* Wg = (gA == 0) ? wf : (gA == 1) ? wi : (gA == 2) ? wo : wc;
  const float* Ug = (gA == 0) ? uf : (gA == 1) ? ui : (gA == 2) ? uo : uc;
  const float* Bg = (gA == 0) ? bf : (gA == 1) ? bi : (gA == 2) ? bo : bc;

  Frag16 fr;
#pragma unroll
  for (int e = 0; e < 4; ++e) {
    const int k0 = 8 * q + 2 * e, k1 = k0 + 1;
    float v0, v1;
    if (sel == 0) {
      v0 = (k0 < F) ? Wg[k0 * H + jj] : (k0 == F ? Bg[jj] : 0.f);
      v1 = (k1 < F) ? Wg[k1 * H + jj] : 0.f;
    } else {
      v0 = (k0 < H) ? Ug[k0 * H + jj] : 0.f;
      v1 = (k1 < H) ? Ug[k1 * H + jj] : 0.f;
    }
    Pack2 p; p.h2 = __float22bfloat162_rn(float2{v0, v1});
    fr.u32[e] = p.u;
  }
  ws[(m * 2 + sel) * 64 + lane] = fr.v;   // [m][sel][lane] -> coalesced reads
}

// ---- main: barrier-free, wave-private LDS rows.
// LDS = 20,480 B EXACTLY -> LDS permits 8 blocks/CU (one generation for the
// 2048-block grid). launch_bounds (256,4): compiler allocates naturally
// (~52 VGPR, spill-free per R10); 52 <= 64 so HW still co-schedules 8
// blocks/CU. R12's (256,8) starved the allocator to 32 VGPR + 88MB spill.
__global__ __launch_bounds__(256, 4) void lstm_main(
    const float* __restrict__ x,
    const bf16x8* __restrict__ wsfrag,
    float* __restrict__ out)
{
  const int tid  = threadIdx.x;
  const int lane = tid & 63;
  const int wv   = tid >> 6;
  const int r15  = lane & 15;
  const int q    = lane >> 4;
  const int b0   = blockIdx.x * BPB;
  const int w0   = 16 * wv;

  const float* xwave = x + (size_t)(b0 + w0) * (T * F);   // contiguous 9.6 KB
  float*       owave = out + (size_t)(b0 + w0) * (T * H); // contiguous 6.4 KB

  // xsb: bf16 x tile in fragment layout. Row r: hw k=0..29 = bf16(x), hw30 =
  // 1.0 (bias col), hw31 = 0, hw32..39 pad. 5,120 B.
  __shared__ __align__(16) unsigned xsb[BPB * XRS];
  // hist: bf16 h history, row layout [t][24] (jj 0..19 + 4 dead slots).
  // Serves BOTH the recurrent fh reads and the final drain. 15,360 B.
  // Row stride 60 dw -> 2-way bank aliasing (free); uint2 reads 8B-aligned.
  __shared__ __align__(16) unsigned short hist[BPB * HRS];

  // ---- ZERO this wave's hist rows (R11 NaN fix). fh reads dead slots
  // (hw 20..23 per t-block) and block t's hw 0..7 before they're written;
  // those must be 0.0, not uninit garbage (bf16 Inf/NaN * 0 = NaN in MFMA).
  {
    uint4* hz = (uint4*)(hist + w0 * HRS);   // wave-private 3,840 B, 16B-aligned
    const uint4 z = uint4{0u, 0u, 0u, 0u};
#pragma unroll
    for (int k = 0; k < 4; ++k) {
      int idx = lane + 64 * k;
      if (idx < 240) hz[idx] = z;
    }
  }

  // prologue: 10 coalesced dwordx4 fragment loads
  bf16x8 wfrag[5], ufrag[5];
#pragma unroll
  for (int m = 0; m < 5; ++m) {
    wfrag[m] = wsfrag[(m * 2 + 0) * 64 + lane];
    ufrag[m] = wsfrag[(m * 2 + 1) * 64 + lane];
  }

  // wave-local bias init: each wave writes its own 16 rows (lane 0..15 only)
  if (lane < 16) xsb[(w0 + lane) * XRS + 15] = 0x00003F80u;

  // stage x(t=0): slot s: r=s>>4, cs=s&15 (15 of 16 active), cols 2cs,2cs+1
#pragma unroll
  for (int j = 0; j < 4; ++j) {
    int s = lane + 64 * j;
    int r = s >> 4, cs = s & 15;
    if (cs < 15) {
      float2 v = *(const float2*)(xwave + r * (T * F) + 2 * cs);
      Pack2 p; p.h2 = __float22bfloat162_rn(v);
      xsb[(w0 + r) * XRS + cs] = p.u;
    }
  }

  float cst[5];
#pragma unroll
  for (int m = 0; m < 5; ++m) cst[m] = 0.f;
  float2 pf2[4];

#pragma unroll
  for (int t = 0; t < T; ++t) {
    // fx: single b128 from fragment-layout LDS (bias baked in, no cvt)
    Frag16 fx;
    fx.d4 = *(const uint4*)&xsb[(w0 + r15) * XRS + 4 * q];

    // T14: issue next-t global loads now; cvt+LDS-write land after compute
    if (t + 1 < T) {
#pragma unroll
      for (int j = 0; j < 4; ++j) {
        int s = lane + 64 * j;
        int r = s >> 4, cs = s & 15;
        if (cs < 15)
          pf2[j] = *(const float2*)(xwave + r * (T * F) + (t + 1) * F + 2 * cs);
      }
    }

    f32x4 acc[5];
#pragma unroll
    for (int m = 0; m < 5; ++m)
      acc[m] = __builtin_amdgcn_mfma_f32_16x16x32_bf16(
          wfrag[m], fx.v, f32x4{0.f, 0.f, 0.f, 0.f}, 0, 0, 0);

    if (t > 0) {   // recurrent term (t=0: h==0, matches reference)
      // fh from hist: hw 24(t-1)+8q.. ; slots at k>=20 are ZERO (prologue
      // memset / zeroed not-yet-written block-t slots) and meet zero U-rows.
      Frag16 fh;
      const unsigned short* hp = &hist[(w0 + r15) * HRS + 24 * (t - 1) + 8 * q];
      fh.d2[0] = *(const uint2*)(hp);
      fh.d2[1] = *(const uint2*)(hp + 4);
#pragma unroll
      for (int m = 0; m < 5; ++m)
        acc[m] = __builtin_amdgcn_mfma_f32_16x16x32_bf16(
            ufrag[m], fh.v, acc[m], 0, 0, 0);
    }

    // gate math: lane-local (acc[m] = f,i,o,c of hidden jj=4m+q, own row)
#pragma unroll
    for (int m = 0; m < 5; ++m) {
      float fg = sig(acc[m][0]);
      float ig = sig(acc[m][1]);
      float og = sig(acc[m][2]);
      float ch = tanh_s(acc[m][3]);
      float cn = fmaf(fg, cst[m], ig * ch);
      cst[m] = cn;
      float hn = og * tanh_s(cn);
      hist[(w0 + r15) * HRS + 24 * t + 4 * m + q] = f2bf(hn);
    }

    // write staged x(t+1) (after this t's fx read -- program order)
    if (t + 1 < T) {
#pragma unroll
      for (int j = 0; j < 4; ++j) {
        int s = lane + 64 * j;
        int r = s >> 4, cs = s & 15;
        if (cs < 15) {
          Pack2 p; p.h2 = __float22bfloat162_rn(pf2[j]);
          xsb[(w0 + r) * XRS + cs] = p.u;
        }
      }
    }
  }

  // drain: wave's contiguous 6.4 KB out slab, full-line float4 stores.
  // g in [0,400): out dwords 4g..4g+3 = row r=g/25, cols c4..c4+3 (c4=4(g%25));
  // src hw = 24*(c4/20) + c4%20 (never crosses a t-block: 20 % 4 == 0).
#pragma unroll
  for (int k = 0; k < 7; ++k) {
    unsigned g = lane + 64 * k;
    if (g < 400) {
      unsigned r = g / 25u, c4 = 4 * (g % 25u);
      unsigned tb = c4 / 20u, j0 = c4 % 20u;
      uint2 pv = *(const uint2*)&hist[(w0 + r) * HRS + 24 * tb + j0];
      float4 v;
      v.x = __uint_as_float(pv.x << 16);
      v.y = __uint_as_float(pv.x & 0xFFFF0000u);
      v.z = __uint_as_float(pv.y << 16);
      v.w = __uint_as_float(pv.y & 0xFFFF0000u);
      *(float4*)(owave + 4 * g) = v;
    }
  }
}

} // namespace

extern "C" void kernel_launch(void* const* d_in, const int* in_sizes, int n_in,
                              void* d_out, int out_size, void* d_ws, size_t ws_size,
                              hipStream_t stream) {
  const float* x  = (const float*)d_in[0];
  const float* wf = (const float*)d_in[1];
  const float* wi = (const float*)d_in[2];
  const float* wo = (const float*)d_in[3];
  const float* wc = (const float*)d_in[4];
  const float* uf = (const float*)d_in[5];
  const float* ui = (const float*)d_in[6];
  const float* uo = (const float*)d_in[7];
  const float* uc = (const float*)d_in[8];
  const float* bf = (const float*)d_in[9];
  const float* bi = (const float*)d_in[10];
  const float* bo = (const float*)d_in[11];
  const float* bc = (const float*)d_in[12];
  float* out = (float*)d_out;
  bf16x8* ws = (bf16x8*)d_ws;   // needs 10,240 B

  hipLaunchKernelGGL(lstm_pack, dim3(3), dim3(256), 0, stream,
                     wf, wi, wo, wc, uf, ui, uo, uc, bf, bi, bo, bc, ws);
  hipLaunchKernelGGL(lstm_main, dim3(BATCH / BPB), dim3(256), 0, stream,
                     x, ws, out);
}

// Round 14
// 39.068 us; speedup vs baseline: 2.5604x; 1.0343x over previous
//
#include <hip/hip_runtime.h>
#include <hip/hip_bf16.h>

namespace {

constexpr int T = 5, F = 30, H = 20;
constexpr int BATCH = 131072;
constexpr int BPB = 64;    // batch rows per block (32 per wave, 2 waves/block)
constexpr int XRS = 20;    // xsb row stride in dwords (40 halfwords / 80 B)
constexpr int HRS = 120;   // hist row stride in halfwords (240 B / 60 dwords)

typedef __attribute__((ext_vector_type(8))) short bf16x8;
typedef __attribute__((ext_vector_type(4))) float f32x4;

union Frag16 { uint2 d2[2]; uint4 d4; unsigned u32[4]; bf16x8 v; };
union Pack2 { __hip_bfloat162 h2; unsigned u; };

__device__ __forceinline__ float sig(float v) {
  return __builtin_amdgcn_rcpf(1.0f + __builtin_amdgcn_exp2f(v * -1.44269504f));
}
// tanh(v) = 2*sigmoid(2v) - 1; saturates correctly at +-inf, no NaN paths.
__device__ __forceinline__ float tanh_s(float v) {
  return fmaf(2.0f,
              __builtin_amdgcn_rcpf(1.0f + __builtin_amdgcn_exp2f(v * -2.88539008f)),
              -1.0f);
}
// round-to-nearest-even f32 -> bf16 bits (inputs tanh-bounded, no NaN/inf)
__device__ __forceinline__ unsigned short f2bf(float f) {
  unsigned u = __float_as_uint(f);
  return (unsigned short)((u + 0x7FFFu + ((u >> 16) & 1u)) >> 16);
}

// ---- setup: pre-pack the 640 MFMA A-fragments into d_ws (unchanged) ----
// Invariant: U rows k>=20 are ZERO and W row k=31 is ZERO; bias at k==30.
__global__ void lstm_pack(
    const float* __restrict__ wf, const float* __restrict__ wi,
    const float* __restrict__ wo, const float* __restrict__ wc,
    const float* __restrict__ uf, const float* __restrict__ ui,
    const float* __restrict__ uo, const float* __restrict__ uc,
    const float* __restrict__ bf, const float* __restrict__ bi,
    const float* __restrict__ bo, const float* __restrict__ bc,
    bf16x8* __restrict__ ws)
{
  const int i = blockIdx.x * 256 + threadIdx.x;
  if (i >= 640) return;
  const int lane = i & 63, sel = (i >> 6) & 1, m = i >> 7;
  const int r15 = lane & 15, q = lane >> 4;
  const int gA = r15 & 3, jA = r15 >> 2;
  const int jj = 4 * m + jA;

  const float* Wg = (gA == 0) ? wf : (gA == 1) ? wi : (gA == 2) ? wo : wc;
  const float* Ug = (gA == 0) ? uf : (gA == 1) ? ui : (gA == 2) ? uo : uc;
  const float* Bg = (gA == 0) ? bf : (gA == 1) ? bi : (gA == 2) ? bo : bc;

  Frag16 fr;
#pragma unroll
  for (int e = 0; e < 4; ++e) {
    const int k0 = 8 * q + 2 * e, k1 = k0 + 1;
    float v0, v1;
    if (sel == 0) {
      v0 = (k0 < F) ? Wg[k0 * H + jj] : (k0 == F ? Bg[jj] : 0.f);
      v1 = (k1 < F) ? Wg[k1 * H + jj] : 0.f;
    } else {
      v0 = (k0 < H) ? Ug[k0 * H + jj] : 0.f;
      v1 = (k1 < H) ? Ug[k1 * H + jj] : 0.f;
    }
    Pack2 p; p.h2 = __float22bfloat162_rn(float2{v0, v1});
    fr.u32[e] = p.u;
  }
  ws[(m * 2 + sel) * 64 + lane] = fr.v;
}

// ---- main: barrier-free; each WAVE owns TWO independent 16-row chains
// (tiles A=rows w0..w0+15, B=w0+16..w0+31) interleaved in the instruction
// stream -> static ILP fills the per-chain LDS/MFMA/transcendental stalls
// (immune to wave convoying, the R13 diagnosis). 128-thread blocks.
__global__ __launch_bounds__(128, 3) void lstm_main(
    const float* __restrict__ x,
    const bf16x8* __restrict__ wsfrag,
    float* __restrict__ out)
{
  const int tid  = threadIdx.x;
  const int lane = tid & 63;
  const int wv   = tid >> 6;          // 0..1
  const int r15  = lane & 15;
  const int q    = lane >> 4;
  const int b0   = blockIdx.x * BPB;
  const int w0   = 32 * wv;           // wave's first block-local row

  const float* xwave = x + (size_t)(b0 + w0) * (T * F);   // contiguous 19.2 KB
  float*       owave = out + (size_t)(b0 + w0) * (T * H); // contiguous 12.8 KB

  __shared__ __align__(16) unsigned xsb[BPB * XRS];        //  5,120 B
  __shared__ __align__(16) unsigned short hist[BPB * HRS]; // 15,360 B

  // zero this wave's 32 hist rows (NaN fix: fh overreach must see 0.0)
  {
    uint4* hz = (uint4*)(hist + w0 * HRS);   // 7,680 B = 480 uint4
    const uint4 z = uint4{0u, 0u, 0u, 0u};
#pragma unroll
    for (int k = 0; k < 8; ++k) {
      int idx = lane + 64 * k;
      if (idx < 480) hz[idx] = z;
    }
  }

  // fragments (shared by both chains -> amortized)
  bf16x8 wfrag[5], ufrag[5];
#pragma unroll
  for (int m = 0; m < 5; ++m) {
    wfrag[m] = wsfrag[(m * 2 + 0) * 64 + lane];
    ufrag[m] = wsfrag[(m * 2 + 1) * 64 + lane];
  }

  // bias/zero dword (hw30=1.0, hw31=0) for the wave's 32 rows
  if (lane < 32) xsb[(w0 + lane) * XRS + 15] = 0x00003F80u;

  // stage x(t=0): 480 float2 slots (s: r=s>>4 in 0..31, cs=s&15, cs<15)
#pragma unroll
  for (int j = 0; j < 8; ++j) {
    int s = lane + 64 * j;
    int r = s >> 4, cs = s & 15;
    if (cs < 15) {
      float2 v = *(const float2*)(xwave + r * (T * F) + 2 * cs);
      Pack2 p; p.h2 = __float22bfloat162_rn(v);
      xsb[(w0 + r) * XRS + cs] = p.u;
    }
  }

  float cstA[5], cstB[5];
#pragma unroll
  for (int m = 0; m < 5; ++m) { cstA[m] = 0.f; cstB[m] = 0.f; }
  float2 pf2[8];

  const int rowA = w0 + r15, rowB = w0 + 16 + r15;

#pragma unroll
  for (int t = 0; t < T; ++t) {
    // fx for both chains (independent b128 reads)
    Frag16 fxA, fxB;
    fxA.d4 = *(const uint4*)&xsb[rowA * XRS + 4 * q];
    fxB.d4 = *(const uint4*)&xsb[rowB * XRS + 4 * q];

    // T14: issue next-t global loads now
    if (t + 1 < T) {
#pragma unroll
      for (int j = 0; j < 8; ++j) {
        int s = lane + 64 * j;
        int r = s >> 4, cs = s & 15;
        if (cs < 15)
          pf2[j] = *(const float2*)(xwave + r * (T * F) + (t + 1) * F + 2 * cs);
      }
    }

    f32x4 accA[5], accB[5];
#pragma unroll
    for (int m = 0; m < 5; ++m) {
      accA[m] = __builtin_amdgcn_mfma_f32_16x16x32_bf16(
          wfrag[m], fxA.v, f32x4{0.f, 0.f, 0.f, 0.f}, 0, 0, 0);
      accB[m] = __builtin_amdgcn_mfma_f32_16x16x32_bf16(
          wfrag[m], fxB.v, f32x4{0.f, 0.f, 0.f, 0.f}, 0, 0, 0);
    }

    if (t > 0) {   // recurrent term (t=0: h==0)
      Frag16 fhA, fhB;
      const unsigned short* hpA = &hist[rowA * HRS + 24 * (t - 1) + 8 * q];
      const unsigned short* hpB = &hist[rowB * HRS + 24 * (t - 1) + 8 * q];
      fhA.d2[0] = *(const uint2*)(hpA);
      fhA.d2[1] = *(const uint2*)(hpA + 4);
      fhB.d2[0] = *(const uint2*)(hpB);
      fhB.d2[1] = *(const uint2*)(hpB + 4);
#pragma unroll
      for (int m = 0; m < 5; ++m) {
        accA[m] = __builtin_amdgcn_mfma_f32_16x16x32_bf16(
            ufrag[m], fhA.v, accA[m], 0, 0, 0);
        accB[m] = __builtin_amdgcn_mfma_f32_16x16x32_bf16(
            ufrag[m], fhB.v, accB[m], 0, 0, 0);
      }
    }

    // gate math, chains interleaved (A[m] then B[m]) for ILP
#pragma unroll
    for (int m = 0; m < 5; ++m) {
      {
        float fg = sig(accA[m][0]);
        float ig = sig(accA[m][1]);
        float og = sig(accA[m][2]);
        float ch = tanh_s(accA[m][3]);
        float cn = fmaf(fg, cstA[m], ig * ch);
        cstA[m] = cn;
        hist[rowA * HRS + 24 * t + 4 * m + q] = f2bf(og * tanh_s(cn));
      }
      {
        float fg = sig(accB[m][0]);
        float ig = sig(accB[m][1]);
        float og = sig(accB[m][2]);
        float ch = tanh_s(accB[m][3]);
        float cn = fmaf(fg, cstB[m], ig * ch);
        cstB[m] = cn;
        hist[rowB * HRS + 24 * t + 4 * m + q] = f2bf(og * tanh_s(cn));
      }
    }

    // write staged x(t+1) (after this t's fx reads -- program order)
    if (t + 1 < T) {
#pragma unroll
      for (int j = 0; j < 8; ++j) {
        int s = lane + 64 * j;
        int r = s >> 4, cs = s & 15;
        if (cs < 15) {
          Pack2 p; p.h2 = __float22bfloat162_rn(pf2[j]);
          xsb[(w0 + r) * XRS + cs] = p.u;
        }
      }
    }
  }

  // drain: wave's contiguous 12.8 KB out slab, full-line float4 stores.
  // g in [0,800): r=g/25, c4=4*(g%25); src hw = 24*(c4/20)+c4%20.
#pragma unroll
  for (int k = 0; k < 13; ++k) {
    unsigned g = lane + 64 * k;
    if (g < 800) {
      unsigned r = g / 25u, c4 = 4 * (g % 25u);
      unsigned tb = c4 / 20u, j0 = c4 % 20u;
      uint2 pv = *(const uint2*)&hist[(w0 + r) * HRS + 24 * tb + j0];
      float4 v;
      v.x = __uint_as_float(pv.x << 16);
      v.y = __uint_as_float(pv.x & 0xFFFF0000u);
      v.z = __uint_as_float(pv.y << 16);
      v.w = __uint_as_float(pv.y & 0xFFFF0000u);
      *(float4*)(owave + 4 * g) = v;
    }
  }
}

} // namespace

extern "C" void kernel_launch(void* const* d_in, const int* in_sizes, int n_in,
                              void* d_out, int out_size, void* d_ws, size_t ws_size,
                              hipStream_t stream) {
  const float* x  = (const float*)d_in[0];
  const float* wf = (const float*)d_in[1];
  const float* wi = (const float*)d_in[2];
  const float* wo = (const float*)d_in[3];
  const float* wc = (const float*)d_in[4];
  const float* uf = (const float*)d_in[5];
  const float* ui = (const float*)d_in[6];
  const float* uo = (const float*)d_in[7];
  const float* uc = (const float*)d_in[8];
  const float* bf = (const float*)d_in[9];
  const float* bi = (const float*)d_in[10];
  const float* bo = (const float*)d_in[11];
  const float* bc = (const float*)d_in[12];
  float* out = (float*)d_out;
  bf16x8* ws = (bf16x8*)d_ws;   // needs 10,240 B

  hipLaunchKernelGGL(lstm_pack, dim3(3), dim3(256), 0, stream,
                     wf, wi, wo, wc, uf, ui, uo, uc, bf, bi, bo, bc, ws);
  hipLaunchKernelGGL(lstm_main, dim3(BATCH / BPB), dim3(128), 0, stream,
                     x, ws, out);
}

// Round 15
// 38.677 us; speedup vs baseline: 2.5863x; 1.0101x over previous
//
#include <hip/hip_runtime.h>
#include <hip/hip_bf16.h>

namespace {

constexpr int T = 5, F = 30, H = 20;
constexpr int BATCH = 131072;
constexpr int BPB = 64;    // batch rows per block (16 per wave)
constexpr int HRS = 120;   // drain-buffer row stride in halfwords (240 B)

typedef __attribute__((ext_vector_type(8))) short bf16x8;
typedef __attribute__((ext_vector_type(4))) float f32x4;

union Frag16 { unsigned u32[4]; bf16x8 v; };
union Pack2 { __hip_bfloat162 h2; unsigned u; };

__device__ __forceinline__ float sig(float v) {
  return __builtin_amdgcn_rcpf(1.0f + __builtin_amdgcn_exp2f(v * -1.44269504f));
}
// tanh(v) = 2*sigmoid(2v) - 1; saturates correctly at +-inf, no NaN paths.
__device__ __forceinline__ float tanh_s(float v) {
  return fmaf(2.0f,
              __builtin_amdgcn_rcpf(1.0f + __builtin_amdgcn_exp2f(v * -2.88539008f)),
              -1.0f);
}

// ---- setup: pre-pack 640 MFMA A-fragments into d_ws ----
// item i: lane = i&63, sel = (i>>6)&1 (0=W,1=U), m = i>>7.
// W (sel=0): identity k; row hidx = 4*jj + gate; bias at k==30; k==31 zero.
// U (sel=1): PERMUTED k-axis. Slot s = 8q+i holds U row kappa(s) = 4i+q for
// i<5, ZERO for i>=5. This makes the B-side h-fragment register-local in the
// main kernel: lane (r15,q) supplies exactly its own h[4m+q] values.
__global__ void lstm_pack(
    const float* __restrict__ wf, const float* __restrict__ wi,
    const float* __restrict__ wo, const float* __restrict__ wc,
    const float* __restrict__ uf, const float* __restrict__ ui,
    const float* __restrict__ uo, const float* __restrict__ uc,
    const float* __restrict__ bf, const float* __restrict__ bi,
    const float* __restrict__ bo, const float* __restrict__ bc,
    bf16x8* __restrict__ ws)
{
  const int i = blockIdx.x * 256 + threadIdx.x;
  if (i >= 640) return;
  const int lane = i & 63, sel = (i >> 6) & 1, m = i >> 7;
  const int r15 = lane & 15, q = lane >> 4;
  const int gA = r15 & 3, jA = r15 >> 2;
  const int jj = 4 * m + jA;

  const float* Wg = (gA == 0) ? wf : (gA == 1) ? wi : (gA == 2) ? wo : wc;
  const float* Ug = (gA == 0) ? uf : (gA == 1) ? ui : (gA == 2) ? uo : uc;
  const float* Bg = (gA == 0) ? bf : (gA == 1) ? bi : (gA == 2) ? bo : bc;

  Frag16 fr;
#pragma unroll
  for (int e = 0; e < 4; ++e) {
    float v0, v1;
    if (sel == 0) {
      const int k0 = 8 * q + 2 * e, k1 = k0 + 1;
      v0 = (k0 < F) ? Wg[k0 * H + jj] : (k0 == F ? Bg[jj] : 0.f);
      v1 = (k1 < F) ? Wg[k1 * H + jj] : 0.f;
    } else {
      const int i0 = 2 * e, i1 = 2 * e + 1;          // slot index within group
      v0 = (i0 < 5) ? Ug[(4 * i0 + q) * H + jj] : 0.f;   // kappa = 4*i + q
      v1 = (i1 < 5) ? Ug[(4 * i1 + q) * H + jj] : 0.f;
    }
    Pack2 p; p.h2 = __float22bfloat162_rn(float2{v0, v1});
    fr.u32[e] = p.u;
  }
  ws[(m * 2 + sel) * 64 + lane] = fr.v;   // [m][sel][lane] -> coalesced reads
}

// ---- main: NO LDS, NO barriers, NO cross-lane in the t-loop.
// fx: direct global float2 loads (wave = 16 rows x 128B contiguous chunks).
// fh: the lane's own previous-t h values, packed bf16 (U k-permutation).
// LDS is used only once, as the output-drain transpose buffer.
__global__ __launch_bounds__(256, 3) void lstm_main(
    const float* __restrict__ x,
    const bf16x8* __restrict__ wsfrag,
    float* __restrict__ out)
{
  const int tid  = threadIdx.x;
  const int lane = tid & 63;
  const int wv   = tid >> 6;
  const int r15  = lane & 15;
  const int q    = lane >> 4;
  const int b0   = blockIdx.x * BPB;
  const int w0   = 16 * wv;

  // lane's own x row: base byte offset r15*600 + t*120 + q*32 (all mult-of-8)
  const float* xrow = x + (size_t)(b0 + w0 + r15) * (T * F);
  float*       owave = out + (size_t)(b0 + w0) * (T * H); // wave slab, 6.4 KB

  __shared__ __align__(16) unsigned short hist[BPB * HRS]; // 15,360 B drain buf

  // prologue: 10 coalesced dwordx4 fragment loads
  bf16x8 wfrag[5], ufrag[5];
#pragma unroll
  for (int m = 0; m < 5; ++m) {
    wfrag[m] = wsfrag[(m * 2 + 0) * 64 + lane];
    ufrag[m] = wsfrag[(m * 2 + 1) * 64 + lane];
  }

  // x load offsets (floats): k = 8q + {0,2,4,6}; 4th load shifted down for
  // q==3 so k=30,31 (which would run past the row/buffer) are never touched.
  const int xo0 = 8 * q, xo1 = 8 * q + 2, xo2 = 8 * q + 4;
  const int xo3 = (q == 3) ? (8 * q + 4) : (8 * q + 6);   // q3: re-read k28,29

  float2 xbuf[2][4];
#pragma unroll
  for (int j = 0; j < 1; ++j) {
    xbuf[0][0] = *(const float2*)(xrow + xo0);
    xbuf[0][1] = *(const float2*)(xrow + xo1);
    xbuf[0][2] = *(const float2*)(xrow + xo2);
    xbuf[0][3] = *(const float2*)(xrow + xo3);
  }

  float cst[5];
#pragma unroll
  for (int m = 0; m < 5; ++m) cst[m] = 0.f;

  unsigned pd[T][3];              // packed bf16 h history (static indices)
  unsigned ph0 = 0, ph1 = 0, ph2 = 0;   // previous-t packed h

#pragma unroll
  for (int t = 0; t < T; ++t) {
    // prefetch x(t+1) now; consumed next iteration (latency under compute)
    if (t + 1 < T) {
      const float* xp = xrow + (t + 1) * F;
      xbuf[(t + 1) & 1][0] = *(const float2*)(xp + xo0);
      xbuf[(t + 1) & 1][1] = *(const float2*)(xp + xo1);
      xbuf[(t + 1) & 1][2] = *(const float2*)(xp + xo2);
      xbuf[(t + 1) & 1][3] = *(const float2*)(xp + xo3);
    }

    // build fx in registers: 4 cvt_pk + q3 bias patch (no LDS, no shuffle)
    Frag16 fx;
    {
      Pack2 p0, p1, p2, p3;
      p0.h2 = __float22bfloat162_rn(xbuf[t & 1][0]);
      p1.h2 = __float22bfloat162_rn(xbuf[t & 1][1]);
      p2.h2 = __float22bfloat162_rn(xbuf[t & 1][2]);
      p3.h2 = __float22bfloat162_rn(xbuf[t & 1][3]);
      fx.u32[0] = p0.u;
      fx.u32[1] = p1.u;
      // q<3: slots {8q+4,8q+5}=p2, {8q+6,8q+7}=p3.
      // q=3: load3 re-read k28,29 -> slots {28,29}=p3(==p2), {30,31}={1,0}.
      fx.u32[2] = (q == 3) ? p3.u : p2.u;
      fx.u32[3] = (q == 3) ? 0x00003F80u : p3.u;
    }

    f32x4 acc[5];
#pragma unroll
    for (int m = 0; m < 5; ++m)
      acc[m] = __builtin_amdgcn_mfma_f32_16x16x32_bf16(
          wfrag[m], fx.v, f32x4{0.f, 0.f, 0.f, 0.f}, 0, 0, 0);

    if (t > 0) {   // recurrent term: fh = lane's OWN packed h (U k-permuted)
      Frag16 fh;
      fh.u32[0] = ph0;   // {h[m0], h[m1]}
      fh.u32[1] = ph1;   // {h[m2], h[m3]}
      fh.u32[2] = ph2;   // {h[m4], 0}
      fh.u32[3] = 0u;    // zero slots (U rows zero there)
#pragma unroll
      for (int m = 0; m < 5; ++m)
        acc[m] = __builtin_amdgcn_mfma_f32_16x16x32_bf16(
            ufrag[m], fh.v, acc[m], 0, 0, 0);
    }

    // gate math: lane-local (acc[m] = f,i,o,c of hidden jj=4m+q, own row)
    float hn[5];
#pragma unroll
    for (int m = 0; m < 5; ++m) {
      float fg = sig(acc[m][0]);
      float ig = sig(acc[m][1]);
      float og = sig(acc[m][2]);
      float ch = tanh_s(acc[m][3]);
      float cn = fmaf(fg, cst[m], ig * ch);
      cst[m] = cn;
      hn[m] = og * tanh_s(cn);
    }
    // pack h -> bf16 pairs: feeds next-t fh AND the output history
    {
      Pack2 a, b, c;
      a.h2 = __float22bfloat162_rn(float2{hn[0], hn[1]});
      b.h2 = __float22bfloat162_rn(float2{hn[2], hn[3]});
      c.h2 = __float22bfloat162_rn(float2{hn[4], 0.f});
      ph0 = a.u; ph1 = b.u; ph2 = c.u;
      pd[t][0] = a.u; pd[t][1] = b.u; pd[t][2] = c.u;
    }
  }

  // ---- drain: registers -> LDS (transpose) -> coalesced float4 stores ----
  // lane's values: jj = 4m+q at halfword 24t + 4m + q of row (w0+r15).
  {
    unsigned short* hrow = hist + (w0 + r15) * HRS;
#pragma unroll
    for (int t = 0; t < T; ++t) {
      hrow[24 * t +  0 + q] = (unsigned short)(pd[t][0]);
      hrow[24 * t +  4 + q] = (unsigned short)(pd[t][0] >> 16);
      hrow[24 * t +  8 + q] = (unsigned short)(pd[t][1]);
      hrow[24 * t + 12 + q] = (unsigned short)(pd[t][1] >> 16);
      hrow[24 * t + 16 + q] = (unsigned short)(pd[t][2]);
    }
  }
  // wave-private rows; within-wave DS ordering is program order -> no barrier.
  // g in [0,400): out dwords 4g..4g+3 = row r=g/25, cols c4=4*(g%25);
  // src hw = 24*(c4/20) + c4%20 (20%4==0 -> never crosses a t-block).
#pragma unroll
  for (int k = 0; k < 7; ++k) {
    unsigned g = lane + 64 * k;
    if (g < 400) {
      unsigned r = g / 25u, c4 = 4 * (g % 25u);
      unsigned tb = c4 / 20u, j0 = c4 % 20u;
      uint2 pv = *(const uint2*)&hist[(w0 + r) * HRS + 24 * tb + j0];
      float4 v;
      v.x = __uint_as_float(pv.x << 16);
      v.y = __uint_as_float(pv.x & 0xFFFF0000u);
      v.z = __uint_as_float(pv.y << 16);
      v.w = __uint_as_float(pv.y & 0xFFFF0000u);
      *(float4*)(owave + 4 * g) = v;
    }
  }
}

} // namespace

extern "C" void kernel_launch(void* const* d_in, const int* in_sizes, int n_in,
                              void* d_out, int out_size, void* d_ws, size_t ws_size,
                              hipStream_t stream) {
  const float* x  = (const float*)d_in[0];
  const float* wf = (const float*)d_in[1];
  const float* wi = (const float*)d_in[2];
  const float* wo = (const float*)d_in[3];
  const float* wc = (const float*)d_in[4];
  const float* uf = (const float*)d_in[5];
  const float* ui = (const float*)d_in[6];
  const float* uo = (const float*)d_in[7];
  const float* uc = (const float*)d_in[8];
  const float* bf = (const float*)d_in[9];
  const float* bi = (const float*)d_in[10];
  const float* bo = (const float*)d_in[11];
  const float* bc = (const float*)d_in[12];
  float* out = (float*)d_out;
  bf16x8* ws = (bf16x8*)d_ws;   // needs 10,240 B

  hipLaunchKernelGGL(lstm_pack, dim3(3), dim3(256), 0, stream,
                     wf, wi, wo, wc, uf, ui, uo, uc, bf, bi, bo, bc, ws);
  hipLaunchKernelGGL(lstm_main, dim3(BATCH / BPB), dim3(256), 0, stream,
                     x, ws, out);
}

// Round 16
// 38.619 us; speedup vs baseline: 2.5902x; 1.0015x over previous
//
#include <hip/hip_runtime.h>
#include <hip/hip_bf16.h>

namespace {

constexpr int T = 5, F = 30, H = 20;
constexpr int BATCH = 131072;
constexpr int BPB = 64;    // batch rows per block (16 per wave)
constexpr int HRS = 120;   // drain-buffer row stride in halfwords (240 B)

typedef __attribute__((ext_vector_type(8))) short bf16x8;
typedef __attribute__((ext_vector_type(4))) float f32x4;

union Frag16 { unsigned u32[4]; bf16x8 v; };
union Pack2 { __hip_bfloat162 h2; unsigned u; };

__device__ __forceinline__ float sig(float v) {
  return __builtin_amdgcn_rcpf(1.0f + __builtin_amdgcn_exp2f(v * -1.44269504f));
}
// tanh(v) = 2*sigmoid(2v) - 1; saturates correctly at +-inf, no NaN paths.
__device__ __forceinline__ float tanh_s(float v) {
  return fmaf(2.0f,
              __builtin_amdgcn_rcpf(1.0f + __builtin_amdgcn_exp2f(v * -2.88539008f)),
              -1.0f);
}

// ---- setup: pre-pack 640 MFMA A-fragments into d_ws ----
// item i: lane = i&63, sel = (i>>6)&1 (0=W,1=U), m = i>>7.
// W (sel=0): identity k; row hidx = 4*jj + gate; bias at k==30; k==31 zero.
// U (sel=1): PERMUTED k-axis: slot s = 8q+i holds U row kappa(s) = 4i+q for
// i<5, ZERO for i>=5 -> the main kernel's h-fragment is register-local.
__global__ void lstm_pack(
    const float* __restrict__ wf, const float* __restrict__ wi,
    const float* __restrict__ wo, const float* __restrict__ wc,
    const float* __restrict__ uf, const float* __restrict__ ui,
    const float* __restrict__ uo, const float* __restrict__ uc,
    const float* __restrict__ bf, const float* __restrict__ bi,
    const float* __restrict__ bo, const float* __restrict__ bc,
    bf16x8* __restrict__ ws)
{
  const int i = blockIdx.x * 256 + threadIdx.x;
  if (i >= 640) return;
  const int lane = i & 63, sel = (i >> 6) & 1, m = i >> 7;
  const int r15 = lane & 15, q = lane >> 4;
  const int gA = r15 & 3, jA = r15 >> 2;
  const int jj = 4 * m + jA;

  const float* Wg = (gA == 0) ? wf : (gA == 1) ? wi : (gA == 2) ? wo : wc;
  const float* Ug = (gA == 0) ? uf : (gA == 1) ? ui : (gA == 2) ? uo : uc;
  const float* Bg = (gA == 0) ? bf : (gA == 1) ? bi : (gA == 2) ? bo : bc;

  Frag16 fr;
#pragma unroll
  for (int e = 0; e < 4; ++e) {
    float v0, v1;
    if (sel == 0) {
      const int k0 = 8 * q + 2 * e, k1 = k0 + 1;
      v0 = (k0 < F) ? Wg[k0 * H + jj] : (k0 == F ? Bg[jj] : 0.f);
      v1 = (k1 < F) ? Wg[k1 * H + jj] : 0.f;
    } else {
      const int i0 = 2 * e, i1 = 2 * e + 1;
      v0 = (i0 < 5) ? Ug[(4 * i0 + q) * H + jj] : 0.f;   // kappa = 4*i + q
      v1 = (i1 < 5) ? Ug[(4 * i1 + q) * H + jj] : 0.f;
    }
    Pack2 p; p.h2 = __float22bfloat162_rn(float2{v0, v1});
    fr.u32[e] = p.u;
  }
  ws[(m * 2 + sel) * 64 + lane] = fr.v;   // [m][sel][lane] -> coalesced reads
}

// ---- main: the t-loop touches NO memory at all (no global, no LDS, no
// cross-lane). The lane's whole x panel (20 float2) is burst-loaded in the
// prologue and kept as 20 packed-bf16 dwords; h recurrence is register-local
// via the U k-permutation. LDS used once as the output-drain buffer.
__global__ __launch_bounds__(256, 4) void lstm_main(
    const float* __restrict__ x,
    const bf16x8* __restrict__ wsfrag,
    float* __restrict__ out)
{
  const int tid  = threadIdx.x;
  const int lane = tid & 63;
  const int wv   = tid >> 6;
  const int r15  = lane & 15;
  const int q    = lane >> 4;
  const int b0   = blockIdx.x * BPB;
  const int w0   = 16 * wv;

  const float* xrow = x + (size_t)(b0 + w0 + r15) * (T * F);
  float*       owave = out + (size_t)(b0 + w0) * (T * H); // wave slab, 6.4 KB

  __shared__ __align__(16) unsigned short hist[BPB * HRS]; // 15,360 B drain buf

  // prologue A: 10 coalesced dwordx4 fragment loads
  bf16x8 wfrag[5], ufrag[5];
#pragma unroll
  for (int m = 0; m < 5; ++m) {
    wfrag[m] = wsfrag[(m * 2 + 0) * 64 + lane];
    ufrag[m] = wsfrag[(m * 2 + 1) * 64 + lane];
  }

  // prologue B: burst-load the lane's ENTIRE x panel (20 float2, one vmcnt
  // FIFO, latency paid once) and convert to packed bf16 with bias patch.
  // Offsets: k = 8q + {0,2,4}; 4th pair shifted for q==3 (re-reads k28,29)
  // so k=30,31 are never touched; slot {30,31} gets {1.0, 0} = bias column.
  const int xo0 = 8 * q, xo1 = 8 * q + 2, xo2 = 8 * q + 4;
  const int xo3 = (q == 3) ? (8 * q + 4) : (8 * q + 6);

  float2 xf[T][4];
#pragma unroll
  for (int t = 0; t < T; ++t) {
    const float* xp = xrow + t * F;
    xf[t][0] = *(const float2*)(xp + xo0);
    xf[t][1] = *(const float2*)(xp + xo1);
    xf[t][2] = *(const float2*)(xp + xo2);
    xf[t][3] = *(const float2*)(xp + xo3);
  }
  unsigned xpk[T][4];
#pragma unroll
  for (int t = 0; t < T; ++t) {
    Pack2 p0, p1, p2, p3;
    p0.h2 = __float22bfloat162_rn(xf[t][0]);
    p1.h2 = __float22bfloat162_rn(xf[t][1]);
    p2.h2 = __float22bfloat162_rn(xf[t][2]);
    p3.h2 = __float22bfloat162_rn(xf[t][3]);
    xpk[t][0] = p0.u;
    xpk[t][1] = p1.u;
    xpk[t][2] = (q == 3) ? p3.u : p2.u;
    xpk[t][3] = (q == 3) ? 0x00003F80u : p3.u;
  }

  float cst[5];
#pragma unroll
  for (int m = 0; m < 5; ++m) cst[m] = 0.f;

  unsigned pd[T][3];                    // packed bf16 h history (static idx)
  unsigned ph0 = 0, ph1 = 0, ph2 = 0;   // previous-t packed h

#pragma unroll
  for (int t = 0; t < T; ++t) {
    Frag16 fx;
    fx.u32[0] = xpk[t][0];
    fx.u32[1] = xpk[t][1];
    fx.u32[2] = xpk[t][2];
    fx.u32[3] = xpk[t][3];

    f32x4 acc[5];
#pragma unroll
    for (int m = 0; m < 5; ++m)
      acc[m] = __builtin_amdgcn_mfma_f32_16x16x32_bf16(
          wfrag[m], fx.v, f32x4{0.f, 0.f, 0.f, 0.f}, 0, 0, 0);

    if (t > 0) {   // recurrent term: fh = lane's OWN packed h (U k-permuted)
      Frag16 fh;
      fh.u32[0] = ph0;   // {h[m0], h[m1]}
      fh.u32[1] = ph1;   // {h[m2], h[m3]}
      fh.u32[2] = ph2;   // {h[m4], 0}
      fh.u32[3] = 0u;    // zero slots (U rows zero there)
#pragma unroll
      for (int m = 0; m < 5; ++m)
        acc[m] = __builtin_amdgcn_mfma_f32_16x16x32_bf16(
            ufrag[m], fh.v, acc[m], 0, 0, 0);
    }

    // gate math: lane-local (acc[m] = f,i,o,c of hidden jj=4m+q, own row)
    float hn[5];
#pragma unroll
    for (int m = 0; m < 5; ++m) {
      float fg = sig(acc[m][0]);
      float ig = sig(acc[m][1]);
      float og = sig(acc[m][2]);
      float ch = tanh_s(acc[m][3]);
      float cn = fmaf(fg, cst[m], ig * ch);
      cst[m] = cn;
      hn[m] = og * tanh_s(cn);
    }
    {
      Pack2 a, b, c;
      a.h2 = __float22bfloat162_rn(float2{hn[0], hn[1]});
      b.h2 = __float22bfloat162_rn(float2{hn[2], hn[3]});
      c.h2 = __float22bfloat162_rn(float2{hn[4], 0.f});
      ph0 = a.u; ph1 = b.u; ph2 = c.u;
      pd[t][0] = a.u; pd[t][1] = b.u; pd[t][2] = c.u;
    }
  }

  // ---- drain: registers -> LDS (transpose) -> coalesced float4 stores ----
  {
    unsigned short* hrow = hist + (w0 + r15) * HRS;
#pragma unroll
    for (int t = 0; t < T; ++t) {
      hrow[24 * t +  0 + q] = (unsigned short)(pd[t][0]);
      hrow[24 * t +  4 + q] = (unsigned short)(pd[t][0] >> 16);
      hrow[24 * t +  8 + q] = (unsigned short)(pd[t][1]);
      hrow[24 * t + 12 + q] = (unsigned short)(pd[t][1] >> 16);
      hrow[24 * t + 16 + q] = (unsigned short)(pd[t][2]);
    }
  }
  // wave-private rows; within-wave DS ordering is program order -> no barrier.
#pragma unroll
  for (int k = 0; k < 7; ++k) {
    unsigned g = lane + 64 * k;
    if (g < 400) {
      unsigned r = g / 25u, c4 = 4 * (g % 25u);
      unsigned tb = c4 / 20u, j0 = c4 % 20u;
      uint2 pv = *(const uint2*)&hist[(w0 + r) * HRS + 24 * tb + j0];
      float4 v;
      v.x = __uint_as_float(pv.x << 16);
      v.y = __uint_as_float(pv.x & 0xFFFF0000u);
      v.z = __uint_as_float(pv.y << 16);
      v.w = __uint_as_float(pv.y & 0xFFFF0000u);
      *(float4*)(owave + 4 * g) = v;
    }
  }
}

} // namespace

extern "C" void kernel_launch(void* const* d_in, const int* in_sizes, int n_in,
                              void* d_out, int out_size, void* d_ws, size_t ws_size,
                              hipStream_t stream) {
  const float* x  = (const float*)d_in[0];
  const float* wf = (const float*)d_in[1];
  const float* wi = (const float*)d_in[2];
  const float* wo = (const float*)d_in[3];
  const float* wc = (const float*)d_in[4];
  const float* uf = (const float*)d_in[5];
  const float* ui = (const float*)d_in[6];
  const float* uo = (const float*)d_in[7];
  const float* uc = (const float*)d_in[8];
  const float* bf = (const float*)d_in[9];
  const float* bi = (const float*)d_in[10];
  const float* bo = (const float*)d_in[11];
  const float* bc = (const float*)d_in[12];
  float* out = (float*)d_out;
  bf16x8* ws = (bf16x8*)d_ws;   // needs 10,240 B

  hipLaunchKernelGGL(lstm_pack, dim3(3), dim3(256), 0, stream,
                     wf, wi, wo, wc, uf, ui, uo, uc, bf, bi, bo, bc, ws);
  hipLaunchKernelGGL(lstm_main, dim3(BATCH / BPB), dim3(256), 0, stream,
                     x, ws, out);
}